// Round 1
// baseline (443.494 us; speedup 1.0000x reference)
//
#include <hip/hip_runtime.h>
#include <hip/hip_bf16.h>
#include <math.h>

// Problem constants (N,C,H,W) = (16,128,128,128)
#define CN      128
#define HWN     16384
#define NBATCH  16
#define PLANE   (CN * HWN)
#define TSTRIDE ((size_t)NBATCH * PLANE)   // elems per tensor in kqv buf

typedef __attribute__((ext_vector_type(8))) short  short8;   // 8 bf16 = 4 VGPR
typedef __attribute__((ext_vector_type(4))) float  float4v;  // MFMA C/D

__device__ __forceinline__ unsigned short f2b(float f) {
    __hip_bfloat16 h = __float2bfloat16(f);
    return *reinterpret_cast<unsigned short*>(&h);
}
__device__ __forceinline__ unsigned packbf(float lo, float hi) {
    return (unsigned)f2b(lo) | ((unsigned)f2b(hi) << 16);
}

// ---------------------------------------------------------------------------
// Prep: weights -> bf16 wbf[o'][c] (o' = tensor*128+o, c contiguous), biases
// -> f32 bias[384].
// ---------------------------------------------------------------------------
__global__ void prep_kernel(const float* __restrict__ wk, const float* __restrict__ bk,
                            const float* __restrict__ wq, const float* __restrict__ bq,
                            const float* __restrict__ wv, const float* __restrict__ bv,
                            unsigned short* __restrict__ wbf, float* __restrict__ bias)
{
    int i = blockIdx.x * 256 + threadIdx.x;   // 0..49151
    int tensor = i >> 14, oc = i & 16383;
    const float* w = tensor == 0 ? wk : (tensor == 1 ? wq : wv);
    wbf[i] = f2b(w[oc]);
    if (i < 384) {
        const float* b = i < 128 ? bk : (i < 256 ? bq : bv);
        bias[i] = b[i & 127];
    }
}

// ---------------------------------------------------------------------------
// Phase A (MFMA, operand-swapped): kqv[o'][n][ch][hw] bf16 = W x X + bias.
// A = X tile (M = 64 spatial), B = W (N = o).  D rows = 4 consecutive hw per
// lane -> one uint2 (4xbf16) store per (mt,nt): 24 vector stores/thread vs 96
// scalar.  Staging: 8 x float4 loads/thread (16 B/lane) into the stride-68
// transposed LDS tile (write conflicts ~4-way but only 4 writes/thread).
// ---------------------------------------------------------------------------
__global__ __launch_bounds__(256) void kqv_kernel(
    const float* __restrict__ x, const unsigned short* __restrict__ wbf,
    const float* __restrict__ bias, unsigned short* __restrict__ kqv)
{
    __shared__ unsigned Xl[64 * 68];   // [hw][c/2], 17 KiB

    const int n   = blockIdx.y;
    const int hw0 = blockIdx.x * 64;
    const int t    = threadIdx.x;
    const int lane = t & 63, wv = t >> 6;
    const int l15  = lane & 15, quad = lane >> 4;

    // ---- stage x tile: thread t loads 8 c-rows x 4 hw as float4 ----
    {
        const int hwg = (t & 15) * 4;
        const int c0  = (t >> 4) * 8;
        const float* xp = x + (size_t)n * PLANE + (size_t)c0 * HWN + hw0 + hwg;
        float v[8][4];
        #pragma unroll
        for (int j = 0; j < 8; ++j)
            *(float4*)v[j] = *(const float4*)(xp + (size_t)j * HWN);
        #pragma unroll
        for (int jj = 0; jj < 4; ++jj) {
            uint4 u;
            u.x = packbf(v[0][jj], v[1][jj]);
            u.y = packbf(v[2][jj], v[3][jj]);
            u.z = packbf(v[4][jj], v[5][jj]);
            u.w = packbf(v[6][jj], v[7][jj]);
            *(uint4*)&Xl[(hwg + jj) * 68 + c0 / 2] = u;
        }
    }
    __syncthreads();

    // ---- A fragments (X, M = spatial): 4 m-tiles x 4 k, hoisted ----
    short8 afr[4][4];
    #pragma unroll
    for (int mt = 0; mt < 4; ++mt)
        #pragma unroll
        for (int k = 0; k < 4; ++k)
            afr[mt][k] = *(const short8*)&Xl[(mt * 16 + l15) * 68 + quad * 4 + k * 16];

    // ---- 6 o-tiles of 16 per wave (o-strip = 96) ----
    #pragma unroll
    for (int nt = 0; nt < 6; ++nt) {
        const int ob = wv * 96 + nt * 16;        // o-tile base, 0..368
        const int tensor = ob >> 7;
        const int oc = (ob & 127) + l15;
        short8 wfr[4];                           // B fragments (W, N = o)
        #pragma unroll
        for (int k = 0; k < 4; ++k)
            wfr[k] = *(const short8*)&wbf[(ob + l15) * CN + quad * 8 + k * 32];
        const float b = bias[ob + l15];
        unsigned short* dst = kqv + (size_t)tensor * TSTRIDE
                            + ((size_t)n * CN + oc) * HWN + hw0 + quad * 4;
        #pragma unroll
        for (int mt = 0; mt < 4; ++mt) {
            float4v acc = {b, b, b, b};
            #pragma unroll
            for (int k = 0; k < 4; ++k)
                acc = __builtin_amdgcn_mfma_f32_16x16x32_bf16(afr[mt][k], wfr[k], acc, 0, 0, 0);
            // rows = hw0 + mt*16 + quad*4 + (0..3): 4 consecutive hw -> uint2
            uint2 u;
            u.x = packbf(acc[0], acc[1]);
            u.y = packbf(acc[2], acc[3]);
            *(uint2*)(dst + mt * 16) = u;
        }
    }
}

// ---------------------------------------------------------------------------
// Phase B (MFMA): per (n,o) block (256 thr):
//   GEMM1: S^T[v][w] = sum_h Qt[v][h]*Kt[w][h]  (Kt/Qt = LDS transposes)
//   softmax over w, entirely in registers (in-lane + quad shfl_xor)
//   attn^T bf16 -> LDS (aliases dead Kt)
//   GEMM2 (operand-swapped): A = attn^T rows (M = v, own strip), B = V rows
//   (N = h) -> D rows = 4 consecutive v at fixed h -> float4 epilogue.
//   No barrier between At write and GEMM2: each wave reads only its own rows.
// LDS 68 KiB -> 2 blocks/CU.
// ---------------------------------------------------------------------------
__global__ __launch_bounds__(256) void attn_kernel(
    const unsigned short* __restrict__ kqv, const float* __restrict__ x,
    const float* __restrict__ gamma, float* __restrict__ out)
{
    __shared__ unsigned lds[17408];          // Kt[0:8704) Qt[8704:17408), 68 KiB
    unsigned* Kt = lds;                      // [w][h/2], stride 68 uints
    unsigned* Qt = lds + 8704;               // [v][h/2]
    unsigned short* At = (unsigned short*)lds;  // attn^T [v][w], stride 136 halves (aliases Kt)

    const int no = blockIdx.x;
    const unsigned short* Kg = kqv + (size_t)no * HWN;
    const unsigned short* Qg = Kg + TSTRIDE;
    const unsigned short* Vg = Kg + 2 * TSTRIDE;

    const int t = threadIdx.x, lane = t & 63, wv = t >> 6;
    const int l15 = lane & 15, quad = lane >> 4;

    // ---- stage Kt[w][h], Qt[v][h] (global bf16 [h][w] -> LDS transposed) ----
    #pragma unroll
    for (int p = 0; p < 8; ++p) {
        const int w  = (p & 1) * 64 + lane;
        const int h0 = ((p >> 1) * 4 + wv) * 8;
        unsigned short kv[8], qv[8];
        #pragma unroll
        for (int j = 0; j < 8; ++j) {
            kv[j] = Kg[(h0 + j) * 128 + w];
            qv[j] = Qg[(h0 + j) * 128 + w];
        }
        uint4 a, b;
        a.x = (unsigned)kv[0] | ((unsigned)kv[1] << 16); a.y = (unsigned)kv[2] | ((unsigned)kv[3] << 16);
        a.z = (unsigned)kv[4] | ((unsigned)kv[5] << 16); a.w = (unsigned)kv[6] | ((unsigned)kv[7] << 16);
        b.x = (unsigned)qv[0] | ((unsigned)qv[1] << 16); b.y = (unsigned)qv[2] | ((unsigned)qv[3] << 16);
        b.z = (unsigned)qv[4] | ((unsigned)qv[5] << 16); b.w = (unsigned)qv[6] | ((unsigned)qv[7] << 16);
        *(uint4*)&Kt[w * 68 + h0 / 2] = a;
        *(uint4*)&Qt[w * 68 + h0 / 2] = b;
    }
    __syncthreads();

    // ---- GEMM1: wave handles v-strip of 32 (2 m-tiles x 8 n-tiles x 4 k) ----
    const int v0 = wv * 32;
    float4v acc1[2][8];
    #pragma unroll
    for (int mt = 0; mt < 2; ++mt)
        #pragma unroll
        for (int nt = 0; nt < 8; ++nt) acc1[mt][nt] = (float4v){0.f, 0.f, 0.f, 0.f};

    {
        short8 afr[2][4];
        #pragma unroll
        for (int mt = 0; mt < 2; ++mt)
            #pragma unroll
            for (int k = 0; k < 4; ++k)
                afr[mt][k] = *(const short8*)&Qt[(v0 + mt * 16 + l15) * 68 + quad * 4 + k * 16];
        #pragma unroll
        for (int nt = 0; nt < 8; ++nt) {
            short8 bfr[4];
            #pragma unroll
            for (int k = 0; k < 4; ++k)
                bfr[k] = *(const short8*)&Kt[(nt * 16 + l15) * 68 + quad * 4 + k * 16];
            #pragma unroll
            for (int mt = 0; mt < 2; ++mt)
                #pragma unroll
                for (int k = 0; k < 4; ++k)
                    acc1[mt][nt] = __builtin_amdgcn_mfma_f32_16x16x32_bf16(afr[mt][k], bfr[k], acc1[mt][nt], 0, 0, 0);
        }
    }
    __syncthreads();   // all waves done reading Kt/Qt; At may now overwrite Kt

    // ---- softmax over w (rows of S^T), in registers ----
    const float sc = 0.08838834764831845f;   // 1/sqrt(128)
    #pragma unroll
    for (int mt = 0; mt < 2; ++mt)
        #pragma unroll
        for (int r = 0; r < 4; ++r) {
            float m = -INFINITY;
            #pragma unroll
            for (int nt = 0; nt < 8; ++nt) {
                acc1[mt][nt][r] *= sc;
                m = fmaxf(m, acc1[mt][nt][r]);
            }
            #pragma unroll
            for (int d = 1; d < 16; d <<= 1) m = fmaxf(m, __shfl_xor(m, d, 64));
            float s = 0.f;
            #pragma unroll
            for (int nt = 0; nt < 8; ++nt) {
                const float e = __expf(acc1[mt][nt][r] - m);
                acc1[mt][nt][r] = e;
                s += e;
            }
            #pragma unroll
            for (int d = 1; d < 16; d <<= 1) s += __shfl_xor(s, d, 64);
            const float inv = 1.0f / s;
            const int v = v0 + mt * 16 + quad * 4 + r;
            #pragma unroll
            for (int nt = 0; nt < 8; ++nt)
                At[v * 136 + nt * 16 + l15] = f2b(acc1[mt][nt][r] * inv);
        }
    // NOTE: no __syncthreads here — GEMM2 A-fragments read only this wave's
    // own At rows [v0, v0+32); DS ops are in-order per wave.

    // ---- GEMM2 (swapped): A = At (M = v, own strip), B = V (N = h) ----
    float4v acc2[2][8];
    #pragma unroll
    for (int mt = 0; mt < 2; ++mt)
        #pragma unroll
        for (int nt = 0; nt < 8; ++nt) acc2[mt][nt] = (float4v){0.f, 0.f, 0.f, 0.f};

    {
        short8 pfr[2][4];   // attn^T fragments (k = w contiguous in LDS)
        #pragma unroll
        for (int mt = 0; mt < 2; ++mt)
            #pragma unroll
            for (int k = 0; k < 4; ++k)
                pfr[mt][k] = *(const short8*)&At[(v0 + mt * 16 + l15) * 136 + quad * 8 + k * 32];
        #pragma unroll
        for (int nt = 0; nt < 8; ++nt) {
            short8 vfr[4];  // V rows straight from global (w-contiguous)
            #pragma unroll
            for (int k = 0; k < 4; ++k)
                vfr[k] = *(const short8*)&Vg[(nt * 16 + l15) * 128 + quad * 8 + k * 32];
            #pragma unroll
            for (int mt = 0; mt < 2; ++mt)
                #pragma unroll
                for (int k = 0; k < 4; ++k)
                    acc2[mt][nt] = __builtin_amdgcn_mfma_f32_16x16x32_bf16(pfr[mt][k], vfr[k], acc2[mt][nt], 0, 0, 0);
        }
    }

    // ---- epilogue: out = gamma*O + x, float4 (4 consecutive v per lane) ----
    const float g = gamma[0];
    const float* xp = x + (size_t)no * HWN;
    float*       op = out + (size_t)no * HWN;
    #pragma unroll
    for (int mt = 0; mt < 2; ++mt)
        #pragma unroll
        for (int nt = 0; nt < 8; ++nt) {
            const int h    = nt * 16 + l15;
            const int vcol = v0 + mt * 16 + quad * 4;
            const int idx  = h * 128 + vcol;
            float4 xv = *(const float4*)(xp + idx);
            float4 ov;
            ov.x = fmaf(g, acc2[mt][nt][0], xv.x);
            ov.y = fmaf(g, acc2[mt][nt][1], xv.y);
            ov.z = fmaf(g, acc2[mt][nt][2], xv.z);
            ov.w = fmaf(g, acc2[mt][nt][3], xv.w);
            *(float4*)(op + idx) = ov;
        }
}

// ---------------------------------------------------------------------------
extern "C" void kernel_launch(void* const* d_in, const int* in_sizes, int n_in,
                              void* d_out, int out_size, void* d_ws, size_t ws_size,
                              hipStream_t stream) {
    const float* x     = (const float*)d_in[0];
    const float* wk    = (const float*)d_in[1];
    const float* bk    = (const float*)d_in[2];
    const float* wq    = (const float*)d_in[3];
    const float* bq    = (const float*)d_in[4];
    const float* wv    = (const float*)d_in[5];
    const float* bv    = (const float*)d_in[6];
    const float* gamma = (const float*)d_in[7];
    float* out = (float*)d_out;

    // ws: wbf bf16 (96 KiB) | bias f32 (1.5 KiB) ... | kqv bf16 @ 256 KiB (192 MiB)
    unsigned short* wbf  = (unsigned short*)d_ws;
    float*          bias = (float*)((char*)d_ws + (192 << 10));
    unsigned short* kqv  = (unsigned short*)((char*)d_ws + (256 << 10));

    prep_kernel<<<192, 256, 0, stream>>>(wk, bk, wq, bq, wv, bv, wbf, bias);
    dim3 gA(HWN / 64, NBATCH);
    kqv_kernel<<<gA, 256, 0, stream>>>(x, wbf, bias, kqv);
    attn_kernel<<<NBATCH * CN, 256, 0, stream>>>(kqv, x, gamma, out);
}